// Round 4
// baseline (520.770 us; speedup 1.0000x reference)
//
#include <hip/hip_runtime.h>
#include <hip/hip_bf16.h>

#define DFEAT 64
#define SBSHIFT 9            // 512 rows per superbucket
#define SBROWS 512
#define CAPSHIFT 13          // 8192 edge slots per superbucket region
#define CAP 8192
#define CHUNK 4096           // edges per binA unit
#define RPT 16               // CHUNK/256
#define CURPAD 16            // sbcursor padded: one counter per 64B line
#define GRID 1024            // 4 blocks/CU * 256 CU — co-residency by construction

typedef __attribute__((ext_vector_type(8))) unsigned short ushort8;

static __device__ __forceinline__ unsigned short f2bf(float f) {
    __hip_bfloat16 h = __float2bfloat16(f);   // RNE
    unsigned short u;
    __builtin_memcpy(&u, &h, 2);
    return u;
}

// ---------------------------------------------------------------------------
// R16: fused single kernel WITHOUT hipLaunchCooperativeKernel (R15's failure
// signature — absmax == max|ref| — means the cooperative launch silently
// errored and never ran; phase bodies are the verified R13 ones). Grid sync
// is a hand-rolled generation barrier in workspace:
//   arrive: __syncthreads; t0: release __threadfence (agent scope: XCD-L2
//   writeback per guide G16), device-scope atomicAdd on counter; last block
//   resets counter and bumps generation; others s_sleep-poll generation;
//   acquire __threadfence; __syncthreads.
// Co-residency: __launch_bounds__(256,4) => <=128 VGPR => 4 blocks/CU;
// LDS 20KB => 8/CU; grid = 4*256 = 1024 exactly. All blocks resident, no
// deadlock. Plain <<<>>> launch => graph-capture safe (R13 precedent).
// Phases: [binA(306)+xw(0..735)] -> bar -> [binB(196)+xw(735..1563)] -> bar
// -> spmm grid-stride. sbcursor+barrier zeroed by ONE memset.
// ---------------------------------------------------------------------------

static __device__ __forceinline__ void grid_barrier(int* bar) {
    __syncthreads();
    if (threadIdx.x == 0) {
        __threadfence();   // release: drain this block's writes to device scope
        int g = __hip_atomic_load(&bar[1], __ATOMIC_RELAXED,
                                  __HIP_MEMORY_SCOPE_AGENT);
        int a = __hip_atomic_fetch_add(&bar[0], 1, __ATOMIC_ACQ_REL,
                                       __HIP_MEMORY_SCOPE_AGENT);
        if (a == (int)gridDim.x - 1) {
            __hip_atomic_store(&bar[0], 0, __ATOMIC_RELAXED,
                               __HIP_MEMORY_SCOPE_AGENT);
            __hip_atomic_fetch_add(&bar[1], 1, __ATOMIC_ACQ_REL,
                                   __HIP_MEMORY_SCOPE_AGENT);
        } else {
            while (__hip_atomic_load(&bar[1], __ATOMIC_RELAXED,
                                     __HIP_MEMORY_SCOPE_AGENT) == g)
                __builtin_amdgcn_s_sleep(2);
        }
        __threadfence();   // acquire: invalidate caches before phase reads
    }
    __syncthreads();
}

static __device__ __forceinline__ void binA_unit(
        int u, const int* __restrict__ ei, int E,
        int* __restrict__ sbcursor, int* __restrict__ packed, int* sbuf) {
    int* hist = sbuf;            // 256
    int* cur  = sbuf + 256;      // 256
    int t = threadIdx.x;
    hist[t] = 0;
    __syncthreads();

    int base = u * CHUNK;
    int rv[RPT];
#pragma unroll
    for (int k = 0; k < RPT; k++) {
        int idx = base + k * 256 + t;
        rv[k] = (idx < E) ? ei[idx] : -1;
        if (rv[k] >= 0) atomicAdd(&hist[rv[k] >> SBSHIFT], 1);
    }
    __syncthreads();

    int h = hist[t];
    cur[t] = (h > 0) ? atomicAdd(&sbcursor[t * CURPAD], h) : 0;  // absolute base
    __syncthreads();

#pragma unroll
    for (int k = 0; k < RPT; k++) {
        int idx = base + k * 256 + t;
        if (rv[k] >= 0) {
            int r = rv[k];
            int c = ei[E + idx];
            int sb = r >> SBSHIFT;
            int pos = atomicAdd(&cur[sb], 1);
            if (pos < CAP)
                packed[(sb << CAPSHIFT) + pos] = ((r & (SBROWS - 1)) << 17) | c;
        }
    }
}

static __device__ __forceinline__ void binB_unit(
        int sb, const int* __restrict__ sbcursor, const int* __restrict__ packed,
        int* __restrict__ csr_col, int* __restrict__ row_beg,
        int* __restrict__ row_end, float* __restrict__ dis, int n, int* sbuf) {
    int* rcnt = sbuf;            // 512
    int* rcur = sbuf + 512;      // 512
    int t = threadIdx.x;
    int cnt = min(sbcursor[sb * CURPAD], CAP);
    const int* pk = packed + ((size_t)sb << CAPSHIFT);
    for (int i = t; i < SBROWS; i += 256) rcnt[i] = 0;
    __syncthreads();
    for (int i = t; i < cnt; i += 256) atomicAdd(&rcnt[pk[i] >> 17], 1);
    __syncthreads();
    // exclusive scan of rcnt[512] by wave 0 (8 elems/lane + shfl_up scan)
    if (t < 64) {
        int v[8];
        int run = 0;
#pragma unroll
        for (int k = 0; k < 8; k++) { v[k] = run; run += rcnt[t * 8 + k]; }
        int x = run;
        for (int off = 1; off < 64; off <<= 1) {
            int y = __shfl_up(x, off);
            if (t >= off) x += y;
        }
        int excl = x - run;
#pragma unroll
        for (int k = 0; k < 8; k++) rcur[t * 8 + k] = excl + v[k];
    }
    __syncthreads();
    int rows = min(SBROWS, n - sb * SBROWS);
    for (int rl = t; rl < rows; rl += 256) {
        int beg = (sb << CAPSHIFT) + rcur[rl];
        int d = rcnt[rl];
        int r = sb * SBROWS + rl;
        row_beg[r] = beg;
        row_end[r] = beg + d;
        dis[r] = (d > 0) ? rsqrtf((float)d) : 0.0f;
    }
    __syncthreads();
    for (int i = t; i < cnt; i += 256) {
        int p = pk[i];
        int pos = atomicAdd(&rcur[p >> 17], 1);
        csr_col[(sb << CAPSHIFT) + pos] = p & 0x1FFFF;
    }
}

static __device__ __forceinline__ void xw_unit(
        int v, const float* __restrict__ feat, const float4* sW,
        ushort8* __restrict__ Y, int n) {
    int q = threadIdx.x & 3;
    int lrow = threadIdx.x >> 2;
    int lane = threadIdx.x & 63;
    int qbase = lane & ~3;
    int row = v * 64 + lrow;

    float4 x[4];
    if (row < n) {
        const float4* xp = (const float4*)(feat + (size_t)row * DFEAT) + q * 4;
        x[0] = xp[0]; x[1] = xp[1]; x[2] = xp[2]; x[3] = xp[3];
    } else {
        x[0] = x[1] = x[2] = x[3] = make_float4(0.f, 0.f, 0.f, 0.f);
    }

    float4 acc[4];
#pragma unroll
    for (int j = 0; j < 4; j++) acc[j] = make_float4(0.f, 0.f, 0.f, 0.f);

#pragma unroll
    for (int qp = 0; qp < 4; qp++) {
#pragma unroll
        for (int jj = 0; jj < 4; jj++) {
            float xs[4];
            xs[0] = __shfl(x[jj].x, qbase + qp);
            xs[1] = __shfl(x[jj].y, qbase + qp);
            xs[2] = __shfl(x[jj].z, qbase + qp);
            xs[3] = __shfl(x[jj].w, qbase + qp);
            int k0 = qp * 16 + jj * 4;
#pragma unroll
            for (int c = 0; c < 4; c++) {
                const float4* wrow = &sW[(k0 + c) * 16 + q * 4];
#pragma unroll
                for (int j = 0; j < 4; j++) {
                    float4 w = wrow[j];
                    acc[j].x = fmaf(xs[c], w.x, acc[j].x);
                    acc[j].y = fmaf(xs[c], w.y, acc[j].y);
                    acc[j].z = fmaf(xs[c], w.z, acc[j].z);
                    acc[j].w = fmaf(xs[c], w.w, acc[j].w);
                }
            }
        }
    }

    if (row < n) {
        ushort8 o0, o1;
        o0[0] = f2bf(acc[0].x); o0[1] = f2bf(acc[0].y);
        o0[2] = f2bf(acc[0].z); o0[3] = f2bf(acc[0].w);
        o0[4] = f2bf(acc[1].x); o0[5] = f2bf(acc[1].y);
        o0[6] = f2bf(acc[1].z); o0[7] = f2bf(acc[1].w);
        o1[0] = f2bf(acc[2].x); o1[1] = f2bf(acc[2].y);
        o1[2] = f2bf(acc[2].z); o1[3] = f2bf(acc[2].w);
        o1[4] = f2bf(acc[3].x); o1[5] = f2bf(acc[3].y);
        o1[6] = f2bf(acc[3].z); o1[7] = f2bf(acc[3].w);
        ushort8* Yo = Y + (size_t)row * 8 + q * 2;
        Yo[0] = o0;
        Yo[1] = o1;
    }
}

static __device__ __forceinline__ void spmm_quad(
        int wq, const int* __restrict__ row_beg, const int* __restrict__ row_end,
        const int* __restrict__ csr_col, const float* __restrict__ dis,
        const ushort8* __restrict__ Y, const float* __restrict__ bias,
        float* __restrict__ out, int n) {
    int lane = threadIdx.x & 63;
    int h = lane >> 4;            // which of the wave's four rows (0..3)
    int lq = lane & 15;           // lane within quarter
    int qb = h << 4;              // quarter base lane
    int row = wq * 4 + h;
    bool active = row < n;
    int s = active ? row_beg[row] : 0;
    int e = active ? row_end[row] : 0;
    int sub = lq >> 3;            // edge slot 0..1
    int f8 = lane & 7;            // feat chunk 0..7
    float acc[8] = {0.f, 0.f, 0.f, 0.f, 0.f, 0.f, 0.f, 0.f};
    for (int base = s; base < e; base += 16) {
        int cnt = min(16, e - base);
        int c = 0;
        float dv = 0.f;
        if (lq < cnt) { c = csr_col[base + lq]; dv = dis[c]; }
        for (int i = 0; i < cnt; i += 2) {
            int ce = __shfl(c, qb + i + sub);     // tail slot -> lane with c=0
            float de = __shfl(dv, qb + i + sub);  // -> 0.0f
            ushort8 y = Y[(size_t)ce * 8 + f8];
#pragma unroll
            for (int k = 0; k < 8; k++)
                acc[k] = fmaf(de, __uint_as_float(((unsigned)y[k]) << 16), acc[k]);
        }
    }
    // reduce across the 2 edge slots (bit 3 — stays within the quarter)
#pragma unroll
    for (int k = 0; k < 8; k++)
        acc[k] += __shfl_xor(acc[k], 8);
    if (active && sub == 0) {
        float dr = dis[row];
        float4 b0 = ((const float4*)bias)[f8 * 2];
        float4 b1 = ((const float4*)bias)[f8 * 2 + 1];
        float4 o0, o1;
        o0.x = fmaxf(fmaf(dr, acc[0], b0.x), 0.f);
        o0.y = fmaxf(fmaf(dr, acc[1], b0.y), 0.f);
        o0.z = fmaxf(fmaf(dr, acc[2], b0.z), 0.f);
        o0.w = fmaxf(fmaf(dr, acc[3], b0.w), 0.f);
        o1.x = fmaxf(fmaf(dr, acc[4], b1.x), 0.f);
        o1.y = fmaxf(fmaf(dr, acc[5], b1.y), 0.f);
        o1.z = fmaxf(fmaf(dr, acc[6], b1.z), 0.f);
        o1.w = fmaxf(fmaf(dr, acc[7], b1.w), 0.f);
        float4* op = (float4*)(out + (size_t)row * DFEAT + f8 * 8);
        op[0] = o0;
        op[1] = o1;
    }
}

__global__ __launch_bounds__(256, 4) void fused_kernel(
        const float* __restrict__ feat, const int* __restrict__ ei,
        const float* __restrict__ W, const float* __restrict__ bias,
        float* __restrict__ out, int n, int E,
        int* bar, int* __restrict__ sbcursor, int* __restrict__ packed,
        int* __restrict__ csr_col, int* __restrict__ row_beg,
        int* __restrict__ row_end, float* __restrict__ dis,
        ushort8* __restrict__ Y, int nSB, int binAUnits, int xwSplit,
        int xwUnits) {
    __shared__ __align__(16) float4 sW[DFEAT * 16];   // 16 KB, loaded once
    __shared__ int sbuf[1024];                        // 4 KB phase scratch

    // stage W once per block (used by xw units in P1 and P2)
    for (int i = threadIdx.x; i < DFEAT * 16; i += 256)
        sW[i] = ((const float4*)W)[i];
    __syncthreads();

    // P1: binA + first slice of xw   (sbcursor/bar pre-zeroed by host memset)
    {
        int ph = binAUnits + xwSplit;
        for (int u = blockIdx.x; u < ph; u += gridDim.x) {
            if (u < binAUnits)
                binA_unit(u, ei, E, sbcursor, packed, sbuf);
            else
                xw_unit(u - binAUnits, feat, sW, Y, n);
        }
    }
    grid_barrier(bar);

    // P2: binB + rest of xw
    {
        int ph = nSB + (xwUnits - xwSplit);
        for (int u = blockIdx.x; u < ph; u += gridDim.x) {
            if (u < nSB)
                binB_unit(u, sbcursor, packed, csr_col, row_beg, row_end, dis,
                          n, sbuf);
            else
                xw_unit(xwSplit + (u - nSB), feat, sW, Y, n);
        }
    }
    grid_barrier(bar);

    // P3: spmm, grid-stride over row-quads
    {
        int gw = (int)((blockIdx.x * 256u + threadIdx.x) >> 6);
        int nwq = (n + 3) >> 2;
        int stride = gridDim.x << 2;   // waves in grid
        for (int wq = gw; wq < nwq; wq += stride)
            spmm_quad(wq, row_beg, row_end, csr_col, dis, Y, bias, out, n);
    }
}

// ---------------------------------------------------------------------------
extern "C" void kernel_launch(void* const* d_in, const int* in_sizes, int n_in,
                              void* d_out, int out_size, void* d_ws, size_t ws_size,
                              hipStream_t stream) {
    const float* feat = (const float*)d_in[0];   // [N, 64] f32
    const int*   ei   = (const int*)d_in[1];     // [2, E] int32 (rows then cols)
    const float* W    = (const float*)d_in[2];   // [64, 64] f32
    const float* bias = (const float*)d_in[3];   // [64] f32
    float* out = (float*)d_out;                  // [N, 64] f32

    int n = in_sizes[0] / DFEAT;                 // 100000
    int E = in_sizes[1] / 2;                     // 1250000
    int nSB = (n + SBROWS - 1) >> SBSHIFT;       // 196

    // workspace layout (int units; every region 16B-aligned):
    int* ws = (int*)d_ws;
    size_t o = 0;
    int*   bar      = ws + o; o += 16;           // barrier counter+generation
    int*   sbcursor = ws + o; o += 256 * CURPAD; // padded: 1 counter / 64B line
    float* dis      = (float*)(ws + o); o += (size_t)n;
    int*   row_beg  = ws + o; o += (size_t)n;
    int*   row_end  = ws + o; o += (size_t)n;
    int*   packed   = ws + o; o += (size_t)nSB << CAPSHIFT;
    int*   csr_col  = ws + o; o += (size_t)nSB << CAPSHIFT;
    ushort8* Y      = (ushort8*)(ws + o);        // n * 64 bf16 = n*16 ints

    // one memset covers barrier words + padded cursors (contiguous)
    hipMemsetAsync(ws, 0, (16 + 256 * CURPAD) * sizeof(int), stream);

    int binAUnits = (E + CHUNK - 1) / CHUNK;     // 306
    int xwUnits   = (n + 63) / 64;               // 1563
    // split xw so P2 has exactly GRID units: nSB + (xwUnits - xwSplit) = GRID
    int xwSplit = xwUnits - (GRID - nSB);        // 735
    if (xwSplit < 0) xwSplit = 0;
    if (xwSplit > xwUnits) xwSplit = xwUnits;

    fused_kernel<<<GRID, 256, 0, stream>>>(
        feat, ei, W, bias, out, n, E,
        bar, sbcursor, packed, csr_col, row_beg, row_end, dis, Y,
        nSB, binAUnits, xwSplit, xwUnits);
}

// Round 5
// 156.218 us; speedup vs baseline: 3.3336x; 3.3336x over previous
//
#include <hip/hip_runtime.h>
#include <hip/hip_bf16.h>

#define DFEAT 64
#define SBSHIFT 9            // 512 rows per superbucket
#define SBROWS 512
#define CAPSHIFT 13          // 8192 edge slots per superbucket region
#define CAP 8192
#define CHUNK 4096           // edges per binA block (R10 measured-good)
#define RPT 16               // CHUNK/256
#define CURPAD 16            // sbcursor padded: one counter per 64B line

typedef __attribute__((ext_vector_type(8))) unsigned short ushort8;

static __device__ __forceinline__ unsigned short f2bf(float f) {
    __hip_bfloat16 h = __float2bfloat16(f);   // RNE
    unsigned short u;
    __builtin_memcpy(&u, &h, 2);
    return u;
}

// ---------------------------------------------------------------------------
// R17: REVERT to the round-0 3-dispatch structure (best measured 160.2).
// R15/R16 established: single-kernel fusion via grid barrier is 3.2x WORSE
// on MI355X — device-scope __threadfence compiles to per-XCD L2
// writeback+invalidate, and 2048 of those nuke the caches mid-phase
// (FETCH+WRITE tripled, HBM BW dropped to 625 GB/s latency-bound).
// Dispatch boundaries are cheap; do NOT fuse across dependency edges.
// This round's single change: spmm inner gather loop unrolled x2
// (two ushort8 gathers in flight per lane, same per-lane summation
// order => bit-identical output).
// ---------------------------------------------------------------------------

// ---------------------------------------------------------------------------
// 1) FUSED: binA (blocks [0,binABlocks) — FIRST, overlapping xw) || xw.
//    LDS union: binA 2 KB (hist+cur), xw 16 KB (W).
//    binA: LDS histogram over 512-row superbuckets -> one global atomicAdd
//    per (block,sb) on padded cursors -> direct scatter,
//    payload = (row&511)<<17 | col. Rows held in registers between passes.
//    xw: Y[t] = feat[t] @ W in bf16, quad-cooperative, ONE row per thread
//    (R10 config — R11 dual-stream spilled @256 VGPR; R12 2-row loop lost
//    wave-parallelism. 1 row/thread, 1563 blocks is the measured optimum.)
// ---------------------------------------------------------------------------
__global__ __launch_bounds__(256) void binA_xw_kernel(
        const float* __restrict__ feat, const float* __restrict__ W,
        ushort8* __restrict__ Y, int n,
        const int* __restrict__ ei, int E,
        int* __restrict__ sbcursor, int* __restrict__ packed, int binABlocks) {
    __shared__ __align__(16) char smem[16384];

    if (blockIdx.x < binABlocks) {
        // ---------------- binA part ----------------
        int* hist = (int*)smem;        // 256
        int* cur  = hist + 256;        // 256
        int t = threadIdx.x;
        hist[t] = 0;
        __syncthreads();

        int base = blockIdx.x * CHUNK;
        int rv[RPT];
#pragma unroll
        for (int k = 0; k < RPT; k++) {
            int idx = base + k * 256 + t;
            rv[k] = (idx < E) ? ei[idx] : -1;
            if (rv[k] >= 0) atomicAdd(&hist[rv[k] >> SBSHIFT], 1);
        }
        __syncthreads();

        int h = hist[t];
        cur[t] = (h > 0) ? atomicAdd(&sbcursor[t * CURPAD], h) : 0;  // absolute base
        __syncthreads();

#pragma unroll
        for (int k = 0; k < RPT; k++) {
            int idx = base + k * 256 + t;
            if (rv[k] >= 0) {
                int r = rv[k];
                int c = ei[E + idx];
                int sb = r >> SBSHIFT;
                int pos = atomicAdd(&cur[sb], 1);
                if (pos < CAP)
                    packed[(sb << CAPSHIFT) + pos] = ((r & (SBROWS - 1)) << 17) | c;
            }
        }
    } else {
        // ---------------- xw part (1 row/thread, R10) ----------------
        float4* sW = (float4*)smem;    // 16 KB: W[k][j] as float4 over j
        for (int i = threadIdx.x; i < DFEAT * 16; i += blockDim.x)
            sW[i] = ((const float4*)W)[i];
        __syncthreads();

        int bid = blockIdx.x - binABlocks;
        int q = threadIdx.x & 3;
        int lrow = threadIdx.x >> 2;
        int lane = threadIdx.x & 63;
        int qbase = lane & ~3;
        int row = bid * 64 + lrow;

        float4 x[4];
        if (row < n) {
            const float4* xp = (const float4*)(feat + (size_t)row * DFEAT) + q * 4;
            x[0] = xp[0]; x[1] = xp[1]; x[2] = xp[2]; x[3] = xp[3];
        } else {
            x[0] = x[1] = x[2] = x[3] = make_float4(0.f, 0.f, 0.f, 0.f);
        }

        float4 acc[4];
#pragma unroll
        for (int j = 0; j < 4; j++) acc[j] = make_float4(0.f, 0.f, 0.f, 0.f);

#pragma unroll
        for (int qp = 0; qp < 4; qp++) {
#pragma unroll
            for (int jj = 0; jj < 4; jj++) {
                float xs[4];
                xs[0] = __shfl(x[jj].x, qbase + qp);
                xs[1] = __shfl(x[jj].y, qbase + qp);
                xs[2] = __shfl(x[jj].z, qbase + qp);
                xs[3] = __shfl(x[jj].w, qbase + qp);
                int k0 = qp * 16 + jj * 4;
#pragma unroll
                for (int c = 0; c < 4; c++) {
                    const float4* wrow = &sW[(k0 + c) * 16 + q * 4];
#pragma unroll
                    for (int j = 0; j < 4; j++) {
                        float4 w = wrow[j];
                        acc[j].x = fmaf(xs[c], w.x, acc[j].x);
                        acc[j].y = fmaf(xs[c], w.y, acc[j].y);
                        acc[j].z = fmaf(xs[c], w.z, acc[j].z);
                        acc[j].w = fmaf(xs[c], w.w, acc[j].w);
                    }
                }
            }
        }

        if (row < n) {
            ushort8 o0, o1;
            o0[0] = f2bf(acc[0].x); o0[1] = f2bf(acc[0].y);
            o0[2] = f2bf(acc[0].z); o0[3] = f2bf(acc[0].w);
            o0[4] = f2bf(acc[1].x); o0[5] = f2bf(acc[1].y);
            o0[6] = f2bf(acc[1].z); o0[7] = f2bf(acc[1].w);
            o1[0] = f2bf(acc[2].x); o1[1] = f2bf(acc[2].y);
            o1[2] = f2bf(acc[2].z); o1[3] = f2bf(acc[2].w);
            o1[4] = f2bf(acc[3].x); o1[5] = f2bf(acc[3].y);
            o1[6] = f2bf(acc[3].z); o1[7] = f2bf(acc[3].w);
            ushort8* Yo = Y + (size_t)row * 8 + q * 2;
            Yo[0] = o0;
            Yo[1] = o1;
        }
    }
}

// ---------------------------------------------------------------------------
// 2) binB: per-superbucket counting sort into CSR order (block-private dense
//    region, native int LDS atomics only). Emits row_beg/row_end/dis.
// ---------------------------------------------------------------------------
__global__ void binB_kernel(const int* __restrict__ sbcursor, const int* __restrict__ packed,
                            int* __restrict__ csr_col, int* __restrict__ row_beg,
                            int* __restrict__ row_end, float* __restrict__ dis, int n) {
    __shared__ int rcnt[SBROWS];
    __shared__ int rcur[SBROWS];
    int sb = blockIdx.x;
    int t = threadIdx.x;
    int cnt = min(sbcursor[sb * CURPAD], CAP);
    const int* pk = packed + ((size_t)sb << CAPSHIFT);
    for (int i = t; i < SBROWS; i += 256) rcnt[i] = 0;
    __syncthreads();
    for (int i = t; i < cnt; i += 256) atomicAdd(&rcnt[pk[i] >> 17], 1);
    __syncthreads();
    // exclusive scan of rcnt[512] by wave 0 (8 elems/lane + shfl_up scan)
    if (t < 64) {
        int v[8];
        int run = 0;
#pragma unroll
        for (int k = 0; k < 8; k++) { v[k] = run; run += rcnt[t * 8 + k]; }
        int x = run;
        for (int off = 1; off < 64; off <<= 1) {
            int y = __shfl_up(x, off);
            if (t >= off) x += y;
        }
        int excl = x - run;
#pragma unroll
        for (int k = 0; k < 8; k++) rcur[t * 8 + k] = excl + v[k];
    }
    __syncthreads();
    int rows = min(SBROWS, n - sb * SBROWS);
    for (int rl = t; rl < rows; rl += 256) {
        int beg = (sb << CAPSHIFT) + rcur[rl];
        int d = rcnt[rl];
        int r = sb * SBROWS + rl;
        row_beg[r] = beg;
        row_end[r] = beg + d;
        dis[r] = (d > 0) ? rsqrtf((float)d) : 0.0f;
    }
    __syncthreads();
    for (int i = t; i < cnt; i += 256) {
        int p = pk[i];
        int pos = atomicAdd(&rcur[p >> 17], 1);
        csr_col[(sb << CAPSHIFT) + pos] = p & 0x1FFFF;
    }
}

// ---------------------------------------------------------------------------
// 3) spmm: FOUR rows per wave (one per 16-lane quarter). Quarter layout:
//    2 edge slots (sub) x 8 feat chunks (f8, 16 B bf16 loads). Guard-free
//    inner loop (tail slots shfl from lanes holding c=0/dv=0 -> Y[0] gather,
//    fma adds 0). R17: inner loop unrolled x2 — TWO ushort8 gathers in
//    flight per lane per iteration (slots i and i+2), accumulated in the
//    same per-lane order as before => bit-identical f32 sums. Register
//    accumulate, quarter-local shfl_xor reduce, fused dis[row]/bias/relu
//    epilogue. Zero atomics.
// ---------------------------------------------------------------------------
__global__ __launch_bounds__(256) void spmm_kernel(
        const int* __restrict__ row_beg, const int* __restrict__ row_end,
        const int* __restrict__ csr_col, const float* __restrict__ dis,
        const ushort8* __restrict__ Y, const float* __restrict__ bias,
        float* __restrict__ out, int n) {
    int wid = (int)(((long long)blockIdx.x * blockDim.x + threadIdx.x) >> 6);
    int lane = threadIdx.x & 63;
    int h = lane >> 4;            // which of the wave's four rows (0..3)
    int lq = lane & 15;           // lane within quarter
    int qb = h << 4;              // quarter base lane
    int row = wid * 4 + h;
    bool active = row < n;
    int s = active ? row_beg[row] : 0;
    int e = active ? row_end[row] : 0;
    int sub = lq >> 3;            // edge slot 0..1
    int f8 = lane & 7;            // feat chunk 0..7
    float acc[8] = {0.f, 0.f, 0.f, 0.f, 0.f, 0.f, 0.f, 0.f};
    for (int base = s; base < e; base += 16) {
        int cnt = min(16, e - base);
        int c = 0;
        float dv = 0.f;
        if (lq < cnt) { c = csr_col[base + lq]; dv = dis[c]; }
        for (int i = 0; i < cnt; i += 4) {
            int   ce0 = __shfl(c,  qb + i + sub);      // tail slot -> c=0
            float de0 = __shfl(dv, qb + i + sub);      // -> 0.0f
            int   ce1 = __shfl(c,  qb + i + 2 + sub);
            float de1 = __shfl(dv, qb + i + 2 + sub);
            ushort8 y0 = Y[(size_t)ce0 * 8 + f8];      // two gathers in flight
            ushort8 y1 = Y[(size_t)ce1 * 8 + f8];
#pragma unroll
            for (int k = 0; k < 8; k++)
                acc[k] = fmaf(de0, __uint_as_float(((unsigned)y0[k]) << 16), acc[k]);
#pragma unroll
            for (int k = 0; k < 8; k++)
                acc[k] = fmaf(de1, __uint_as_float(((unsigned)y1[k]) << 16), acc[k]);
        }
    }
    // reduce across the 2 edge slots (bit 3 — stays within the quarter)
#pragma unroll
    for (int k = 0; k < 8; k++)
        acc[k] += __shfl_xor(acc[k], 8);
    if (active && sub == 0) {
        float dr = dis[row];
        float4 b0 = ((const float4*)bias)[f8 * 2];
        float4 b1 = ((const float4*)bias)[f8 * 2 + 1];
        float4 o0, o1;
        o0.x = fmaxf(fmaf(dr, acc[0], b0.x), 0.f);
        o0.y = fmaxf(fmaf(dr, acc[1], b0.y), 0.f);
        o0.z = fmaxf(fmaf(dr, acc[2], b0.z), 0.f);
        o0.w = fmaxf(fmaf(dr, acc[3], b0.w), 0.f);
        o1.x = fmaxf(fmaf(dr, acc[4], b1.x), 0.f);
        o1.y = fmaxf(fmaf(dr, acc[5], b1.y), 0.f);
        o1.z = fmaxf(fmaf(dr, acc[6], b1.z), 0.f);
        o1.w = fmaxf(fmaf(dr, acc[7], b1.w), 0.f);
        float4* op = (float4*)(out + (size_t)row * DFEAT + f8 * 8);
        op[0] = o0;
        op[1] = o1;
    }
}

// ---------------------------------------------------------------------------
extern "C" void kernel_launch(void* const* d_in, const int* in_sizes, int n_in,
                              void* d_out, int out_size, void* d_ws, size_t ws_size,
                              hipStream_t stream) {
    const float* feat = (const float*)d_in[0];   // [N, 64] f32
    const int*   ei   = (const int*)d_in[1];     // [2, E] int32 (rows then cols)
    const float* W    = (const float*)d_in[2];   // [64, 64] f32
    const float* bias = (const float*)d_in[3];   // [64] f32
    float* out = (float*)d_out;                  // [N, 64] f32

    int n = in_sizes[0] / DFEAT;                 // 100000
    int E = in_sizes[1] / 2;                     // 1250000
    int nSB = (n + SBROWS - 1) >> SBSHIFT;       // 196

    // workspace layout (int units; every region 16B-aligned):
    int* ws = (int*)d_ws;
    size_t o = 0;
    int*   sbcursor = ws + o; o += 256 * CURPAD; // padded: 1 counter / 64B line
    float* dis      = (float*)(ws + o); o += (size_t)n;
    int*   row_beg  = ws + o; o += (size_t)n;
    int*   row_end  = ws + o; o += (size_t)n;
    int*   packed   = ws + o; o += (size_t)nSB << CAPSHIFT;
    int*   csr_col  = ws + o; o += (size_t)nSB << CAPSHIFT;
    ushort8* Y      = (ushort8*)(ws + o);        // n * 64 bf16 = n*16 ints

    hipMemsetAsync(sbcursor, 0, 256 * CURPAD * sizeof(int), stream);

    int binABlocks = (E + CHUNK - 1) / CHUNK;    // 306
    int xwBlocks = (n + 63) / 64;                // 1563
    binA_xw_kernel<<<binABlocks + xwBlocks, 256, 0, stream>>>(
        feat, W, Y, n, ei, E, sbcursor, packed, binABlocks);
    binB_kernel<<<nSB, 256, 0, stream>>>(sbcursor, packed, csr_col, row_beg, row_end, dis, n);
    spmm_kernel<<<((n + 3) / 4 + 3) / 4, 256, 0, stream>>>(
        row_beg, row_end, csr_col, dis, Y, bias, out, n);
}